// Round 16
// baseline (59.388 us; speedup 1.0000x reference)
//
#include <hip/hip_runtime.h>
#include <hip/hip_bf16.h>

typedef float f32x4 __attribute__((ext_vector_type(4)));
typedef __bf16 bf16x8 __attribute__((ext_vector_type(8)));

union Frag { unsigned short h[8]; unsigned int u[4]; uint4 u4; bf16x8 b; };

__device__ __forceinline__ unsigned short f2bs(float f){
  __hip_bfloat16 v = __float2bfloat16(f);
  return __builtin_bit_cast(unsigned short, v);
}
// 1-instruction bf16 pair pack (RNE)
__device__ __forceinline__ unsigned int pk2(float a, float b){
  unsigned int r;
  asm("v_cvt_pk_bf16_f32 %0, %1, %2" : "=v"(r) : "v"(a), "v"(b));
  return r;
}
__device__ __forceinline__ Frag packF(f32x4 a, f32x4 b){
  Frag f;
  f.u[0] = pk2(a[0], a[1]); f.u[1] = pk2(a[2], a[3]);
  f.u[2] = pk2(b[0], b[1]); f.u[3] = pk2(b[2], b[3]);
  return f;
}
__device__ __forceinline__ f32x4 relu4(f32x4 v){
  f32x4 r;
  #pragma unroll
  for (int j = 0; j < 4; ++j) r[j] = fmaxf(v[j], 0.f);
  return r;
}
__device__ __forceinline__ float sigmoid_fast(float x){
  return __builtin_amdgcn_rcpf(1.f + __expf(-x));
}

// ---------------------------------------------------------------------------
// Prep (r16 layout): LOOP-RESIDENT frags compacted to [0,40) so the main
// kernel's LDS table is 40KB (was 64KB):
//   [0,8)   W1 cols 0..63   (m*2+s)
//   [8,16)  W2              (8+m*2+s)
//   [16,24) MU cols 0..63   (16+m*2+s)
//   [24,32) ATT1 cols 0..63 (24+m*2+s)
//   [32,40) ATT2            (32+m*2+s)
//   [40,48) MU cols 64..127  - used ONCE (prologue, read from global)
//   [48,56) ATT1 cols 64..127- used ONCE
//   f==56:  r1c[5][68] f32 at ws+3584 (uint4): r1c[R][d]=b1[d]+W1[:,64:]@r2e[R]
// A-frag element (h,j): W[16*m + (lane&15)][32*s + 16*h + 4*(lane>>4) + j]
// ---------------------------------------------------------------------------
__global__ void prep_weights(const float* __restrict__ w1, const float* __restrict__ w2,
                             const float* __restrict__ mu, const float* __restrict__ a1,
                             const float* __restrict__ a2, const float* __restrict__ r2e,
                             const float* __restrict__ b1, uint4* __restrict__ ws){
  const int f = blockIdx.x;
  const int l = threadIdx.x;
  if (f < 56){
    const float* W; int m, s, K;
    if (f < 8)       { W = w1; m = f >> 1;        s = f & 1;            K = 128; }
    else if (f < 16) { W = w2; m = (f - 8) >> 1;  s = (f - 8) & 1;      K = 64;  }
    else if (f < 24) { W = mu; m = (f - 16) >> 1; s = (f - 16) & 1;     K = 128; }
    else if (f < 32) { W = a1; m = (f - 24) >> 1; s = (f - 24) & 1;     K = 128; }
    else if (f < 40) { W = a2; m = (f - 32) >> 1; s = (f - 32) & 1;     K = 64;  }
    else if (f < 48) { W = mu; m = (f - 40) >> 1; s = 2 + ((f - 40) & 1); K = 128; }
    else             { W = a1; m = (f - 48) >> 1; s = 2 + ((f - 48) & 1); K = 128; }
    const int row = 16 * m + (l & 15);
    const int k0  = 32 * s + 4 * (l >> 4);
    Frag fr;
    #pragma unroll
    for (int h = 0; h < 2; ++h)
      #pragma unroll
      for (int j = 0; j < 4; ++j)
        fr.h[4*h + j] = f2bs(W[row * K + k0 + 16*h + j]);
    ws[f * 64 + l] = fr.u4;
  } else {
    // r1c table: thread l = output dim d (exact fp32)
    float* r1c = (float*)(ws + 3584);
    const int d = l;
    for (int R = 0; R < 5; ++R){
      float s = b1[d];
      for (int k = 0; k < 64; ++k)
        s = fmaf(w1[d * 128 + 64 + k], r2e[R * 64 + k], s);
      r1c[R * 68 + d] = s;     // stride 68 floats (bank-spread)
    }
  }
}

// ---------------------------------------------------------------------------
// Main (r16): grid 1024 x 256thr. Block owns 2 nodes; each node split across
// 2 waves (half 0: tiles 0..6, half 1: tiles 7..12), dual-chunk per wave
// (measured ILP optimum, r13). LDS is now 44.9KB (40KB loop frags + bias +
// r1c + merge) -> 3 blocks/CU resident = 12 waves/CU = 3 waves/SIMD (+50%
// over the 68KB/2-block layout). Max-free softmax makes the 2-wave merge a
// pure sum (r7 pattern). Loop-invariant halves hoisted (r15): S1 e_r-half =
// r1c table, S3/S4 q-halves = muq/a1q regs (q-half frags read once from L2).
// NOTE: no min-waves launch_bounds arg (r3: cap => ~1GB scratch spill).
// LDS (44896 B): [0,40960) uint4 wlds[2560]; [40960,42496) float bias[384];
//   [42496,43856) float r1cl[5*68]; [43856,44880) float mAcc[2][2][64];
//   [44880,44896) float mSw[2][2]
// ---------------------------------------------------------------------------
__global__ __launch_bounds__(256)
void uv_agg_main(const int* __restrict__ nodes, const int* __restrict__ huv,
                 const int* __restrict__ hr, const float* __restrict__ u2e,
                 const float* __restrict__ v2e,
                 const float* __restrict__ b1g, const float* __restrict__ b2g,
                 const float* __restrict__ bmg, const float* __restrict__ ba1g,
                 const float* __restrict__ ba2g, const float* __restrict__ a3g,
                 const uint4* __restrict__ wsfrag, float* __restrict__ out){
  extern __shared__ unsigned char smem[];
  uint4* wlds = (uint4*)smem;
  float* bias = (float*)(smem + 40960);
  float* r1cl = (float*)(smem + 42496);
  float* mAcc = (float*)(smem + 43856);   // [ns][half][64]
  float* mSw  = (float*)(smem + 44880);   // [ns][half]

  const int tid  = threadIdx.x;
  const int lane = tid & 63;
  const int wave = tid >> 6;     // 0..3
  const int ns   = wave >> 1;    // node sub-index (0..1)
  const int half = wave & 1;     // 0: tiles 0..6, 1: tiles 7..12
  const int g    = lane >> 4;
  const int r16  = lane & 15;
  const int n    = blockIdx.x * 2 + ns;

  // stage loop frags + biases + r1c into LDS
  #pragma unroll
  for (int i = tid; i < 2560; i += 256) wlds[i] = wsfrag[i];
  for (int i = tid; i < 384; i += 256){
    const int w = i >> 6, d = i & 63;
    const float* src = (w==0)?b1g:(w==1)?b2g:(w==2)?bmg:(w==3)?ba1g:(w==4)?ba2g:a3g;
    bias[i] = src[d];
  }
  {
    const float* r1g = (const float*)(wsfrag + 3584);
    for (int i = tid; i < 340; i += 256) r1cl[i] = r1g[i];
  }
  __syncthreads();

  const uint4* wl = wlds + lane;
  const f32x4* bl = (const f32x4*)bias + g;
  const int* hu  = huv + n * 200;
  const int* hrw = hr  + n * 200;

  // per-node q = v2e[nodes[n]]
  const int item = nodes[n];
  f32x4 qv[4];
  #pragma unroll
  for (int m = 0; m < 4; ++m)
    qv[m] = *(const f32x4*)(v2e + (size_t)item * 64 + 16*m + 4*g);
  Frag qf[2];
  qf[0] = packF(qv[0], qv[1]); qf[1] = packF(qv[2], qv[3]);

  // ONE-TIME: muq = mu_b + MU[:,64:]@q ; a1q = att1_b + ATT1[:,64:]@q
  // (q-half frags read from global/L2 — used exactly once)
  f32x4 muq[4], a1q[4];
  #pragma unroll
  for (int m = 0; m < 4; ++m){
    f32x4 a = bl[2*16 + 4*m];
    {
      Frag w; w.u4 = wsfrag[(40 + m*2 + 0) * 64 + lane];
      a = __builtin_amdgcn_mfma_f32_16x16x32_bf16(w.b, qf[0].b, a, 0, 0, 0);
      w.u4 = wsfrag[(40 + m*2 + 1) * 64 + lane];
      a = __builtin_amdgcn_mfma_f32_16x16x32_bf16(w.b, qf[1].b, a, 0, 0, 0);
    }
    muq[m] = a;
    f32x4 b = bl[3*16 + 4*m];
    {
      Frag w; w.u4 = wsfrag[(48 + m*2 + 0) * 64 + lane];
      b = __builtin_amdgcn_mfma_f32_16x16x32_bf16(w.b, qf[0].b, b, 0, 0, 0);
      w.u4 = wsfrag[(48 + m*2 + 1) * 64 + lane];
      b = __builtin_amdgcn_mfma_f32_16x16x32_bf16(w.b, qf[1].b, b, 0, 0, 0);
    }
    a1q[m] = b;
  }

  float swl = 0.f;                 // per-lane exp-sum (reduced in finale)
  f32x4 accw[4];
  #pragma unroll
  for (int m = 0; m < 4; ++m) accw[m] = (f32x4)(0.f);

  const int nIt = half ? 3 : 4;
  const int t0  = half ? 7 : 0;

  // initial gather: tiles t0, t0+1
  int irA, irB;
  f32x4 urA[4], urB[4];
  {
    const int kA = min(16*t0 + r16, 199);
    const int kB = min(16*t0 + 16 + r16, 199);
    const int iuA = hu[kA]; irA = hrw[kA];
    const int iuB = hu[kB]; irB = hrw[kB];
    const f32x4* ua = (const f32x4*)(u2e + (size_t)iuA * 64);
    const f32x4* ub = (const f32x4*)(u2e + (size_t)iuB * 64);
    #pragma unroll
    for (int s = 0; s < 4; ++s){ urA[s] = ua[4*s + g]; urB[s] = ub[4*s + g]; }
  }

  for (int it = 0; it < nIt; ++it){
    const int tA = t0 + 2*it;
    const int tB = (half == 0 && it == 3) ? 13 : (t0 + 2*it + 1);  // 13 = masked
    Frag b0A[2], b0B[2];
    b0A[0] = packF(urA[0], urA[1]); b0A[1] = packF(urA[2], urA[3]);
    b0B[0] = packF(urB[0], urB[1]); b0B[1] = packF(urB[2], urB[3]);
    const int ircA = irA, ircB = irB;
    const bool vA = (16*tA + r16) < 200;
    const bool vB = (16*tB + r16) < 200;

    // prefetch next pair (independent of this iteration's chains)
    if (it + 1 < nIt){
      const int tAn = t0 + 2*it + 2;
      const int tBn = (half == 0 && it + 1 == 3) ? 13 : (t0 + 2*it + 3);
      const int kA = min(16*tAn + r16, 199);
      const int kB = min(16*tBn + r16, 199);
      const int iuA = hu[kA]; irA = hrw[kA];
      const int iuB = hu[kB]; irB = hrw[kB];
      const f32x4* ua = (const f32x4*)(u2e + (size_t)iuA * 64);
      const f32x4* ub = (const f32x4*)(u2e + (size_t)iuB * 64);
      #pragma unroll
      for (int s = 0; s < 4; ++s){ urA[s] = ua[4*s + g]; urB[s] = ub[4*s + g]; }
    }

    // S1: X = relu(W1a @ e_uv + r1c[ir])   [e_r half precomputed]
    f32x4 XA[4], XB[4];
    __builtin_amdgcn_s_setprio(1);
    #pragma unroll
    for (int m = 0; m < 4; ++m){
      f32x4 aA = *(const f32x4*)&r1cl[ircA*68 + 16*m + 4*g];
      f32x4 aB = *(const f32x4*)&r1cl[ircB*68 + 16*m + 4*g];
      #pragma unroll
      for (int s = 0; s < 2; ++s){
        Frag w; w.u4 = wl[(m*2 + s) * 64];
        aA = __builtin_amdgcn_mfma_f32_16x16x32_bf16(w.b, b0A[s].b, aA, 0, 0, 0);
        aB = __builtin_amdgcn_mfma_f32_16x16x32_bf16(w.b, b0B[s].b, aB, 0, 0, 0);
      }
      XA[m] = relu4(aA); XB[m] = relu4(aB);
    }
    __builtin_amdgcn_s_setprio(0);
    Frag bxA[2], bxB[2];
    bxA[0] = packF(XA[0], XA[1]); bxA[1] = packF(XA[2], XA[3]);
    bxB[0] = packF(XB[0], XB[1]); bxB[1] = packF(XB[2], XB[3]);

    // S2: O = relu(W2 @ X + b2)
    f32x4 OA[4], OB[4];
    __builtin_amdgcn_s_setprio(1);
    #pragma unroll
    for (int m = 0; m < 4; ++m){
      const f32x4 bi = bl[1*16 + 4*m];
      f32x4 aA = bi, aB = bi;
      #pragma unroll
      for (int s = 0; s < 2; ++s){
        Frag w; w.u4 = wl[(8 + m*2 + s) * 64];
        aA = __builtin_amdgcn_mfma_f32_16x16x32_bf16(w.b, bxA[s].b, aA, 0, 0, 0);
        aB = __builtin_amdgcn_mfma_f32_16x16x32_bf16(w.b, bxB[s].b, aB, 0, 0, 0);
      }
      OA[m] = relu4(aA); OB[m] = relu4(aB);
    }
    __builtin_amdgcn_s_setprio(0);
    Frag boA[2], boB[2];
    boA[0] = packF(OA[0], OA[1]); boA[1] = packF(OA[2], OA[3]);
    boB[0] = packF(OB[0], OB[1]); boB[1] = packF(OB[2], OB[3]);

    // S3: gate = sigmoid(MU_O @ O + muq); OG = q + gate*(O-q)
    f32x4 OGA[4], OGB[4];
    __builtin_amdgcn_s_setprio(1);
    #pragma unroll
    for (int m = 0; m < 4; ++m){
      f32x4 aA = muq[m], aB = muq[m];
      #pragma unroll
      for (int s = 0; s < 2; ++s){
        Frag w; w.u4 = wl[(16 + m*2 + s) * 64];
        aA = __builtin_amdgcn_mfma_f32_16x16x32_bf16(w.b, boA[s].b, aA, 0, 0, 0);
        aB = __builtin_amdgcn_mfma_f32_16x16x32_bf16(w.b, boB[s].b, aB, 0, 0, 0);
      }
      #pragma unroll
      for (int j = 0; j < 4; ++j){
        const float gA = sigmoid_fast(aA[j]);
        const float gB = sigmoid_fast(aB[j]);
        OGA[m][j] = fmaf(gA, OA[m][j] - qv[m][j], qv[m][j]);
        OGB[m][j] = fmaf(gB, OB[m][j] - qv[m][j], qv[m][j]);
      }
    }
    __builtin_amdgcn_s_setprio(0);
    Frag bgA[2], bgB[2];
    bgA[0] = packF(OGA[0], OGA[1]); bgA[1] = packF(OGA[2], OGA[3]);
    bgB[0] = packF(OGB[0], OGB[1]); bgB[1] = packF(OGB[2], OGB[3]);

    // S4: A1 = relu(ATT1_O @ OG + a1q)
    f32x4 A1A[4], A1B[4];
    __builtin_amdgcn_s_setprio(1);
    #pragma unroll
    for (int m = 0; m < 4; ++m){
      f32x4 aA = a1q[m], aB = a1q[m];
      #pragma unroll
      for (int s = 0; s < 2; ++s){
        Frag w; w.u4 = wl[(24 + m*2 + s) * 64];
        aA = __builtin_amdgcn_mfma_f32_16x16x32_bf16(w.b, bgA[s].b, aA, 0, 0, 0);
        aB = __builtin_amdgcn_mfma_f32_16x16x32_bf16(w.b, bgB[s].b, aB, 0, 0, 0);
      }
      A1A[m] = relu4(aA); A1B[m] = relu4(aB);
    }
    __builtin_amdgcn_s_setprio(0);
    Frag b4A[2], b4B[2];
    b4A[0] = packF(A1A[0], A1A[1]); b4A[1] = packF(A1A[2], A1A[3]);
    b4B[0] = packF(A1B[0], A1B[1]); b4B[1] = packF(A1B[2], A1B[3]);

    // S5: A2 = relu(ATT2 @ A1 + att2_b); logit = dot(att3_w, A2_row)
    float pA = 0.f, pB = 0.f;
    __builtin_amdgcn_s_setprio(1);
    #pragma unroll
    for (int m = 0; m < 4; ++m){
      const f32x4 bi = bl[4*16 + 4*m];
      f32x4 aA = bi, aB = bi;
      #pragma unroll
      for (int s = 0; s < 2; ++s){
        Frag w; w.u4 = wl[(32 + m*2 + s) * 64];
        aA = __builtin_amdgcn_mfma_f32_16x16x32_bf16(w.b, b4A[s].b, aA, 0, 0, 0);
        aB = __builtin_amdgcn_mfma_f32_16x16x32_bf16(w.b, b4B[s].b, aB, 0, 0, 0);
      }
      aA = relu4(aA); aB = relu4(aB);
      const f32x4 a3m = bl[5*16 + 4*m];
      #pragma unroll
      for (int j = 0; j < 4; ++j){
        pA = fmaf(a3m[j], aA[j], pA);
        pB = fmaf(a3m[j], aB[j], pB);
      }
    }
    __builtin_amdgcn_s_setprio(0);
    pA += __shfl_xor(pA, 16); pA += __shfl_xor(pA, 32);
    pB += __shfl_xor(pB, 16); pB += __shfl_xor(pB, 32);

    // max-free online softmax (logits O(1e-2); guard at 60); es-reduce deferred
    const float eA = vA ? __expf(fminf(pA, 60.f)) : 0.f;
    const float eB = vB ? __expf(fminf(pB, 60.f)) : 0.f;
    swl += eA + eB;
    #pragma unroll
    for (int m = 0; m < 4; ++m)
      #pragma unroll
      for (int j = 0; j < 4; ++j)
        accw[m][j] = fmaf(eA, OGA[m][j], fmaf(eB, OGB[m][j], accw[m][j]));
  }

  // finale: reduce over the 16 row-lanes, publish per (node, half), merge
  #pragma unroll
  for (int o = 1; o < 16; o <<= 1){
    #pragma unroll
    for (int m = 0; m < 4; ++m)
      #pragma unroll
      for (int j = 0; j < 4; ++j)
        accw[m][j] += __shfl_xor(accw[m][j], o);
    swl += __shfl_xor(swl, o);
  }
  if (r16 == 0){
    float* dst = mAcc + (ns * 2 + half) * 64;
    #pragma unroll
    for (int m = 0; m < 4; ++m)
      *(f32x4*)(dst + 16*m + 4*g) = accw[m];
    if (lane == 0) mSw[ns * 2 + half] = swl;
  }
  __syncthreads();
  if (tid < 128){
    const int n2 = tid >> 6, d = tid & 63;
    const float tot = mSw[n2 * 2] + mSw[n2 * 2 + 1];
    const float v = (mAcc[n2 * 128 + d] + mAcc[n2 * 128 + 64 + d]) / tot;
    out[(size_t)(blockIdx.x * 2 + n2) * 64 + d] = v;
  }
}

extern "C" void kernel_launch(void* const* d_in, const int* in_sizes, int n_in,
                              void* d_out, int out_size, void* d_ws, size_t ws_size,
                              hipStream_t stream){
  const int*   nodes = (const int*)  d_in[0];
  const int*   huv   = (const int*)  d_in[1];
  const int*   hr    = (const int*)  d_in[2];
  const float* u2e   = (const float*)d_in[3];
  const float* v2e   = (const float*)d_in[4];
  const float* r2e   = (const float*)d_in[5];
  const float* w1    = (const float*)d_in[6];
  const float* b1    = (const float*)d_in[7];
  const float* w2    = (const float*)d_in[8];
  const float* b2    = (const float*)d_in[9];
  const float* muw   = (const float*)d_in[10];
  const float* mub   = (const float*)d_in[11];
  const float* a1w   = (const float*)d_in[12];
  const float* a1b   = (const float*)d_in[13];
  const float* a2w   = (const float*)d_in[14];
  const float* a2b   = (const float*)d_in[15];
  const float* a3w   = (const float*)d_in[16];
  // d_in[17] = att3_b: constant logit offset -> cancels in softmax.

  const int N = in_sizes[0];            // 2048
  uint4* ws = (uint4*)d_ws;             // 56 frags + r1c (~58KB)

  hipLaunchKernelGGL(prep_weights, dim3(57), dim3(64), 0, stream,
                     w1, w2, muw, a1w, a2w, r2e, b1, ws);
  hipLaunchKernelGGL(uv_agg_main, dim3(N / 2), dim3(256), 44896, stream,
                     nodes, huv, hr, u2e, v2e,
                     b1, b2, mub, a1b, a2b, a3w,
                     (const uint4*)ws, (float*)d_out);
}

// Round 17
// 48.939 us; speedup vs baseline: 1.2135x; 1.2135x over previous
//
#include <hip/hip_runtime.h>
#include <hip/hip_bf16.h>

typedef float f32x4 __attribute__((ext_vector_type(4)));
typedef __bf16 bf16x8 __attribute__((ext_vector_type(8)));

union Frag { unsigned short h[8]; unsigned int u[4]; uint4 u4; bf16x8 b; };

__device__ __forceinline__ unsigned short f2bs(float f){
  __hip_bfloat16 v = __float2bfloat16(f);
  return __builtin_bit_cast(unsigned short, v);
}
// 1-instruction bf16 pair pack (RNE)
__device__ __forceinline__ unsigned int pk2(float a, float b){
  unsigned int r;
  asm("v_cvt_pk_bf16_f32 %0, %1, %2" : "=v"(r) : "v"(a), "v"(b));
  return r;
}
__device__ __forceinline__ Frag packF(f32x4 a, f32x4 b){
  Frag f;
  f.u[0] = pk2(a[0], a[1]); f.u[1] = pk2(a[2], a[3]);
  f.u[2] = pk2(b[0], b[1]); f.u[3] = pk2(b[2], b[3]);
  return f;
}
__device__ __forceinline__ f32x4 relu4(f32x4 v){
  f32x4 r;
  #pragma unroll
  for (int j = 0; j < 4; ++j) r[j] = fmaxf(v[j], 0.f);
  return r;
}
__device__ __forceinline__ float sigmoid_fast(float x){
  return __builtin_amdgcn_rcpf(1.f + __expf(-x));
}

// ---------------------------------------------------------------------------
// Prep: weight matrices -> MFMA A-frag order bf16 (ws[0..4095] uint4), r2e
// B-frags (ws[4096..4735], unused by main, kept for layout stability), and
// r1c[5][68] f32 at ws float offset 4736*4: r1c[R][d] = b1[d] +
// sum_k W1[d][64+k]*r2e[R][k] — the S1 e_r-half GEMM has only 5 possible
// results (NUM_R=5), precomputed exactly in fp32.
// A-frag element (h,j): W[16*m + (lane&15)][32*s + 16*h + 4*(lane>>4) + j]
// ---------------------------------------------------------------------------
__global__ void prep_weights(const float* __restrict__ w1, const float* __restrict__ w2,
                             const float* __restrict__ mu, const float* __restrict__ a1,
                             const float* __restrict__ a2, const float* __restrict__ r2e,
                             const float* __restrict__ b1, uint4* __restrict__ ws){
  const int f = blockIdx.x;
  const int l = threadIdx.x;
  Frag fr;
  if (f < 64){
    const float* W; int m, s, K;
    if (f < 16)      { W = w1; m = f >> 2;        s = f & 3;        K = 128; }
    else if (f < 24) { W = w2; m = (f - 16) >> 1; s = (f - 16) & 1; K = 64;  }
    else if (f < 40) { W = mu; m = (f - 24) >> 2; s = (f - 24) & 3; K = 128; }
    else if (f < 56) { W = a1; m = (f - 40) >> 2; s = (f - 40) & 3; K = 128; }
    else             { W = a2; m = (f - 56) >> 1; s = (f - 56) & 1; K = 64;  }
    const int row = 16 * m + (l & 15);
    const int k0  = 32 * s + 4 * (l >> 4);
    #pragma unroll
    for (int h = 0; h < 2; ++h)
      #pragma unroll
      for (int j = 0; j < 4; ++j)
        fr.h[4*h + j] = f2bs(W[row * K + k0 + 16*h + j]);
    ws[f * 64 + l] = fr.u4;
  } else if (f < 74){
    const int f2 = f - 64;            // 0..9
    const int R = f2 >> 1, sp = f2 & 1;
    const int g = (l >> 4) & 3;
    #pragma unroll
    for (int h = 0; h < 2; ++h)
      #pragma unroll
      for (int j = 0; j < 4; ++j)
        fr.h[4*h + j] = f2bs(r2e[R * 64 + sp * 32 + 16*h + 4*g + j]);
    ws[4096 + f2 * 64 + l] = fr.u4;
  } else {
    // r1c table: thread l = output dim d (exact fp32)
    float* r1c = (float*)(ws + 4736);
    const int d = l;
    for (int R = 0; R < 5; ++R){
      float s = b1[d];
      for (int k = 0; k < 64; ++k)
        s = fmaf(w1[d * 128 + 64 + k], r2e[R * 64 + k], s);
      r1c[R * 68 + d] = s;     // stride 68 floats (bank-spread)
    }
  }
}

// ---------------------------------------------------------------------------
// Main (r15 champion, reverted after r16's split-node regression 47->59us):
// grid 512 x 256thr, wave w owns node n = b*4+w end-to-end. DUAL-CHUNK
// (measured ILP optimum, r13: NC=3 at 252 regs is slower than NC=2 at ~100).
// Loop-invariant GEMM halves hoisted (r15, +11%): S1's e_r half is a
// 5-entry precomputed fp32 table (r1c, LDS acc-init); S3/S4's q halves are
// computed ONCE per wave into muq/a1q regs. 80 MFMAs/iteration (was 128).
// Weight table in LDS (r9: L2 weights 3x worse). Max-free softmax with
// per-lane deferred es-sum. setprio around MFMA clusters (r14: neutral,
// kept as measured-with).
// Lever inventory (all measured): occupancy geometry r7/r16 no-land; ILP-3
// r13 reg-poison; weight pipeline r10 spill; L2 weights r9 3x worse;
// micro-sched r14 null. This structure is the practical latency floor at
// 2 waves/SIMD.
// NOTE: no min-waves launch_bounds arg (r3: cap => ~1GB scratch spill).
// LDS (68432 B): [0,65536) uint4 wlds[4096]; [65536,67072) float bias[384];
//                [67072,68432) float r1cl[5*68]
// ---------------------------------------------------------------------------
__global__ __launch_bounds__(256)
void uv_agg_main(const int* __restrict__ nodes, const int* __restrict__ huv,
                 const int* __restrict__ hr, const float* __restrict__ u2e,
                 const float* __restrict__ v2e,
                 const float* __restrict__ b1g, const float* __restrict__ b2g,
                 const float* __restrict__ bmg, const float* __restrict__ ba1g,
                 const float* __restrict__ ba2g, const float* __restrict__ a3g,
                 const uint4* __restrict__ wsfrag, float* __restrict__ out){
  extern __shared__ unsigned char smem[];
  uint4* wlds = (uint4*)smem;
  float* bias = (float*)(smem + 65536);
  float* r1cl = (float*)(smem + 67072);

  const int tid  = threadIdx.x;
  const int lane = tid & 63;
  const int wave = tid >> 6;
  const int g    = lane >> 4;
  const int r16  = lane & 15;
  const int n    = blockIdx.x * 4 + wave;

  // stage weight frag table + biases + r1c into LDS
  #pragma unroll 4
  for (int i = tid; i < 4096; i += 256) wlds[i] = wsfrag[i];
  for (int i = tid; i < 384; i += 256){
    const int w = i >> 6, d = i & 63;
    const float* src = (w==0)?b1g:(w==1)?b2g:(w==2)?bmg:(w==3)?ba1g:(w==4)?ba2g:a3g;
    bias[i] = src[d];
  }
  {
    const float* r1g = (const float*)(wsfrag + 4736);
    for (int i = tid; i < 340; i += 256) r1cl[i] = r1g[i];
  }
  __syncthreads();

  const uint4* wl = wlds + lane;
  const f32x4* bl = (const f32x4*)bias + g;
  const int* hu  = huv + n * 200;
  const int* hrw = hr  + n * 200;

  // per-node q = v2e[nodes[n]]
  const int item = nodes[n];
  f32x4 qv[4];
  #pragma unroll
  for (int m = 0; m < 4; ++m)
    qv[m] = *(const f32x4*)(v2e + (size_t)item * 64 + 16*m + 4*g);
  Frag qf[2];
  qf[0] = packF(qv[0], qv[1]); qf[1] = packF(qv[2], qv[3]);

  // ONE-TIME: muq = mu_b + MU[:,64:]@q ; a1q = att1_b + ATT1[:,64:]@q
  f32x4 muq[4], a1q[4];
  #pragma unroll
  for (int m = 0; m < 4; ++m){
    f32x4 a = bl[2*16 + 4*m];
    {
      Frag w; w.u4 = wl[(24 + m*4 + 2) * 64];
      a = __builtin_amdgcn_mfma_f32_16x16x32_bf16(w.b, qf[0].b, a, 0, 0, 0);
      w.u4 = wl[(24 + m*4 + 3) * 64];
      a = __builtin_amdgcn_mfma_f32_16x16x32_bf16(w.b, qf[1].b, a, 0, 0, 0);
    }
    muq[m] = a;
    f32x4 b = bl[3*16 + 4*m];
    {
      Frag w; w.u4 = wl[(40 + m*4 + 2) * 64];
      b = __builtin_amdgcn_mfma_f32_16x16x32_bf16(w.b, qf[0].b, b, 0, 0, 0);
      w.u4 = wl[(40 + m*4 + 3) * 64];
      b = __builtin_amdgcn_mfma_f32_16x16x32_bf16(w.b, qf[1].b, b, 0, 0, 0);
    }
    a1q[m] = b;
  }

  float swl = 0.f;                 // per-lane exp-sum (reduced in finale)
  f32x4 accw[4];
  #pragma unroll
  for (int m = 0; m < 4; ++m) accw[m] = (f32x4)(0.f);

  // initial gather: tiles 0 and 1
  int irA, irB;
  f32x4 urA[4], urB[4];
  {
    const int iuA = hu[r16];      irA = hrw[r16];
    const int iuB = hu[16 + r16]; irB = hrw[16 + r16];
    const f32x4* ua = (const f32x4*)(u2e + (size_t)iuA * 64);
    const f32x4* ub = (const f32x4*)(u2e + (size_t)iuB * 64);
    #pragma unroll
    for (int s = 0; s < 4; ++s){ urA[s] = ua[4*s + g]; urB[s] = ub[4*s + g]; }
  }

  for (int it = 0; it < 7; ++it){
    Frag b0A[2], b0B[2];
    b0A[0] = packF(urA[0], urA[1]); b0A[1] = packF(urA[2], urA[3]);
    b0B[0] = packF(urB[0], urB[1]); b0B[1] = packF(urB[2], urB[3]);
    const int ircA = irA, ircB = irB;
    const bool vA = (it < 6) || (r16 < 8);   // tile 12: rows 192..199
    const bool vB = (it < 6);                // tile 13: none

    // prefetch next pair (independent of this iteration's chains)
    if (it < 6){
      const int base = 32*it + 32;
      const int kA = min(base + r16, 199);
      const int kB = min(base + 16 + r16, 199);
      const int iuA = hu[kA]; irA = hrw[kA];
      const int iuB = hu[kB]; irB = hrw[kB];
      const f32x4* ua = (const f32x4*)(u2e + (size_t)iuA * 64);
      const f32x4* ub = (const f32x4*)(u2e + (size_t)iuB * 64);
      #pragma unroll
      for (int s = 0; s < 4; ++s){ urA[s] = ua[4*s + g]; urB[s] = ub[4*s + g]; }
    }

    // S1: X = relu(W1a @ e_uv + r1c[ir])   [e_r half precomputed]
    f32x4 XA[4], XB[4];
    __builtin_amdgcn_s_setprio(1);
    #pragma unroll
    for (int m = 0; m < 4; ++m){
      f32x4 aA = *(const f32x4*)&r1cl[ircA*68 + 16*m + 4*g];
      f32x4 aB = *(const f32x4*)&r1cl[ircB*68 + 16*m + 4*g];
      #pragma unroll
      for (int s = 0; s < 2; ++s){
        Frag w; w.u4 = wl[(m*4 + s) * 64];
        aA = __builtin_amdgcn_mfma_f32_16x16x32_bf16(w.b, b0A[s].b, aA, 0, 0, 0);
        aB = __builtin_amdgcn_mfma_f32_16x16x32_bf16(w.b, b0B[s].b, aB, 0, 0, 0);
      }
      XA[m] = relu4(aA); XB[m] = relu4(aB);
    }
    __builtin_amdgcn_s_setprio(0);
    Frag bxA[2], bxB[2];
    bxA[0] = packF(XA[0], XA[1]); bxA[1] = packF(XA[2], XA[3]);
    bxB[0] = packF(XB[0], XB[1]); bxB[1] = packF(XB[2], XB[3]);

    // S2: O = relu(W2 @ X + b2)
    f32x4 OA[4], OB[4];
    __builtin_amdgcn_s_setprio(1);
    #pragma unroll
    for (int m = 0; m < 4; ++m){
      const f32x4 bi = bl[1*16 + 4*m];
      f32x4 aA = bi, aB = bi;
      #pragma unroll
      for (int s = 0; s < 2; ++s){
        Frag w; w.u4 = wl[(16 + m*2 + s) * 64];
        aA = __builtin_amdgcn_mfma_f32_16x16x32_bf16(w.b, bxA[s].b, aA, 0, 0, 0);
        aB = __builtin_amdgcn_mfma_f32_16x16x32_bf16(w.b, bxB[s].b, aB, 0, 0, 0);
      }
      OA[m] = relu4(aA); OB[m] = relu4(aB);
    }
    __builtin_amdgcn_s_setprio(0);
    Frag boA[2], boB[2];
    boA[0] = packF(OA[0], OA[1]); boA[1] = packF(OA[2], OA[3]);
    boB[0] = packF(OB[0], OB[1]); boB[1] = packF(OB[2], OB[3]);

    // S3: gate = sigmoid(MU_O @ O + muq); OG = q + gate*(O-q)
    f32x4 OGA[4], OGB[4];
    __builtin_amdgcn_s_setprio(1);
    #pragma unroll
    for (int m = 0; m < 4; ++m){
      f32x4 aA = muq[m], aB = muq[m];
      #pragma unroll
      for (int s = 0; s < 2; ++s){
        Frag w; w.u4 = wl[(24 + m*4 + s) * 64];
        aA = __builtin_amdgcn_mfma_f32_16x16x32_bf16(w.b, boA[s].b, aA, 0, 0, 0);
        aB = __builtin_amdgcn_mfma_f32_16x16x32_bf16(w.b, boB[s].b, aB, 0, 0, 0);
      }
      #pragma unroll
      for (int j = 0; j < 4; ++j){
        const float gA = sigmoid_fast(aA[j]);
        const float gB = sigmoid_fast(aB[j]);
        OGA[m][j] = fmaf(gA, OA[m][j] - qv[m][j], qv[m][j]);
        OGB[m][j] = fmaf(gB, OB[m][j] - qv[m][j], qv[m][j]);
      }
    }
    __builtin_amdgcn_s_setprio(0);
    Frag bgA[2], bgB[2];
    bgA[0] = packF(OGA[0], OGA[1]); bgA[1] = packF(OGA[2], OGA[3]);
    bgB[0] = packF(OGB[0], OGB[1]); bgB[1] = packF(OGB[2], OGB[3]);

    // S4: A1 = relu(ATT1_O @ OG + a1q)
    f32x4 A1A[4], A1B[4];
    __builtin_amdgcn_s_setprio(1);
    #pragma unroll
    for (int m = 0; m < 4; ++m){
      f32x4 aA = a1q[m], aB = a1q[m];
      #pragma unroll
      for (int s = 0; s < 2; ++s){
        Frag w; w.u4 = wl[(40 + m*4 + s) * 64];
        aA = __builtin_amdgcn_mfma_f32_16x16x32_bf16(w.b, bgA[s].b, aA, 0, 0, 0);
        aB = __builtin_amdgcn_mfma_f32_16x16x32_bf16(w.b, bgB[s].b, aB, 0, 0, 0);
      }
      A1A[m] = relu4(aA); A1B[m] = relu4(aB);
    }
    __builtin_amdgcn_s_setprio(0);
    Frag b4A[2], b4B[2];
    b4A[0] = packF(A1A[0], A1A[1]); b4A[1] = packF(A1A[2], A1A[3]);
    b4B[0] = packF(A1B[0], A1B[1]); b4B[1] = packF(A1B[2], A1B[3]);

    // S5: A2 = relu(ATT2 @ A1 + att2_b); logit = dot(att3_w, A2_row)
    float pA = 0.f, pB = 0.f;
    __builtin_amdgcn_s_setprio(1);
    #pragma unroll
    for (int m = 0; m < 4; ++m){
      const f32x4 bi = bl[4*16 + 4*m];
      f32x4 aA = bi, aB = bi;
      #pragma unroll
      for (int s = 0; s < 2; ++s){
        Frag w; w.u4 = wl[(56 + m*2 + s) * 64];
        aA = __builtin_amdgcn_mfma_f32_16x16x32_bf16(w.b, b4A[s].b, aA, 0, 0, 0);
        aB = __builtin_amdgcn_mfma_f32_16x16x32_bf16(w.b, b4B[s].b, aB, 0, 0, 0);
      }
      aA = relu4(aA); aB = relu4(aB);
      const f32x4 a3m = bl[5*16 + 4*m];
      #pragma unroll
      for (int j = 0; j < 4; ++j){
        pA = fmaf(a3m[j], aA[j], pA);
        pB = fmaf(a3m[j], aB[j], pB);
      }
    }
    __builtin_amdgcn_s_setprio(0);
    pA += __shfl_xor(pA, 16); pA += __shfl_xor(pA, 32);
    pB += __shfl_xor(pB, 16); pB += __shfl_xor(pB, 32);

    // max-free online softmax (logits O(1e-2); guard at 60); es-reduce deferred
    const float eA = vA ? __expf(fminf(pA, 60.f)) : 0.f;
    const float eB = vB ? __expf(fminf(pB, 60.f)) : 0.f;
    swl += eA + eB;
    #pragma unroll
    for (int m = 0; m < 4; ++m)
      #pragma unroll
      for (int j = 0; j < 4; ++j)
        accw[m][j] = fmaf(eA, OGA[m][j], fmaf(eB, OGB[m][j], accw[m][j]));
  }

  // finale: reduce over the 16 row-lanes (accw and swl), scale, store
  #pragma unroll
  for (int o = 1; o < 16; o <<= 1){
    #pragma unroll
    for (int m = 0; m < 4; ++m)
      #pragma unroll
      for (int j = 0; j < 4; ++j)
        accw[m][j] += __shfl_xor(accw[m][j], o);
    swl += __shfl_xor(swl, o);
  }
  if (r16 == 0){
    const float inv = 1.f / swl;
    #pragma unroll
    for (int m = 0; m < 4; ++m){
      f32x4 v = accw[m];
      #pragma unroll
      for (int j = 0; j < 4; ++j) v[j] *= inv;
      *(f32x4*)(out + (size_t)n * 64 + 16*m + 4*g) = v;
    }
  }
}

extern "C" void kernel_launch(void* const* d_in, const int* in_sizes, int n_in,
                              void* d_out, int out_size, void* d_ws, size_t ws_size,
                              hipStream_t stream){
  const int*   nodes = (const int*)  d_in[0];
  const int*   huv   = (const int*)  d_in[1];
  const int*   hr    = (const int*)  d_in[2];
  const float* u2e   = (const float*)d_in[3];
  const float* v2e   = (const float*)d_in[4];
  const float* r2e   = (const float*)d_in[5];
  const float* w1    = (const float*)d_in[6];
  const float* b1    = (const float*)d_in[7];
  const float* w2    = (const float*)d_in[8];
  const float* b2    = (const float*)d_in[9];
  const float* muw   = (const float*)d_in[10];
  const float* mub   = (const float*)d_in[11];
  const float* a1w   = (const float*)d_in[12];
  const float* a1b   = (const float*)d_in[13];
  const float* a2w   = (const float*)d_in[14];
  const float* a2b   = (const float*)d_in[15];
  const float* a3w   = (const float*)d_in[16];
  // d_in[17] = att3_b: constant logit offset -> cancels in softmax.

  const int N = in_sizes[0];            // 2048
  uint4* ws = (uint4*)d_ws;             // frag table + r2e frags + r1c (~76KB)

  hipLaunchKernelGGL(prep_weights, dim3(75), dim3(64), 0, stream,
                     w1, w2, muw, a1w, a2w, r2e, b1, ws);
  hipLaunchKernelGGL(uv_agg_main, dim3(N / 4), dim3(256), 68432, stream,
                     nodes, huv, hr, u2e, v2e,
                     b1, b2, mub, a1b, a2b, a3w,
                     (const uint4*)ws, (float*)d_out);
}